// Round 1
// baseline (963.008 us; speedup 1.0000x reference)
//
#include <hip/hip_runtime.h>
#include <hip/hip_bf16.h>
#include <cstdint>
#include <cstddef>

typedef __attribute__((ext_vector_type(8))) __bf16 bf16x8;
typedef __attribute__((ext_vector_type(4))) __bf16 bf16x4;
typedef __attribute__((ext_vector_type(4))) float  f32x4;

#define B_  8
#define T_  200
#define U_  100
#define E_  512
#define P_  640
#define H_  512
#define V_  1024

__device__ __forceinline__ void async_ld16(const void* g, void* lds) {
  __builtin_amdgcn_global_load_lds(
      (const __attribute__((address_space(1))) unsigned int*)g,
      (__attribute__((address_space(3))) unsigned int*)lds,
      16, 0, 0);
}

// ---------------- fp32 -> bf16 convert ----------------
__global__ void cvt_bf16_kernel(const float* __restrict__ in, __bf16* __restrict__ out, int n) {
  int i = (blockIdx.x * blockDim.x + threadIdx.x) * 4;
  if (i + 4 <= n) {
    f32x4 v = *(const f32x4*)(in + i);
    bf16x4 o;
    o[0] = (__bf16)v[0]; o[1] = (__bf16)v[1]; o[2] = (__bf16)v[2]; o[3] = (__bf16)v[3];
    *(bf16x4*)(out + i) = o;
  } else {
    for (; i < n; ++i) out[i] = (__bf16)in[i];
  }
}

// ---------------- generic bf16 GEMM: C[M][ldc] = A[M][K] * B[N][K]^T + bias ----------------
// 256 threads = 4 waves (2x2), tile 128x128, BK=32. A,B staged via global_load_lds.
__global__ __launch_bounds__(256)
void gemm_bias_kernel(const __bf16* __restrict__ A, const __bf16* __restrict__ Bm,
                      const float* __restrict__ bias, float* __restrict__ C,
                      int M, int K, int ldc) {
  __shared__ __bf16 As[128 * 32];
  __shared__ __bf16 Bs[128 * 32];

  const int tid  = threadIdx.x;
  const int wave = tid >> 6, lane = tid & 63;
  const int l15  = lane & 15, quad = lane >> 4;
  const int wm   = wave & 1,  wn   = wave >> 1;
  const int m0 = blockIdx.y * 128, n0 = blockIdx.x * 128;

  f32x4 acc[4][4];
#pragma unroll
  for (int i = 0; i < 4; ++i)
#pragma unroll
    for (int j = 0; j < 4; ++j) acc[i][j] = (f32x4){0.f, 0.f, 0.f, 0.f};

  for (int kk = 0; kk < K; kk += 32) {
#pragma unroll
    for (int j = 0; j < 2; ++j) {
      int f   = (wave * 2 + j) * 1024 + lane * 16;  // flat byte offset in 8KB tile
      int row = f >> 6;                             // 64B per row (32 bf16)
      int kb  = (f & 63) >> 1;                      // element offset within row
      int ar  = m0 + row; if (ar >= M) ar = M - 1;  // clamp for partial m-tiles
      async_ld16(A  + (size_t)ar * K + kk + kb,        (char*)As + (wave * 2 + j) * 1024);
      async_ld16(Bm + (size_t)(n0 + row) * K + kk + kb,(char*)Bs + (wave * 2 + j) * 1024);
    }
    __syncthreads();
    bf16x8 af[4], bfr[4];
#pragma unroll
    for (int mi = 0; mi < 4; ++mi)
      af[mi] = *(const bf16x8*)(As + (wm * 64 + mi * 16 + l15) * 32 + quad * 8);
#pragma unroll
    for (int ni = 0; ni < 4; ++ni)
      bfr[ni] = *(const bf16x8*)(Bs + (wn * 64 + ni * 16 + l15) * 32 + quad * 8);
#pragma unroll
    for (int mi = 0; mi < 4; ++mi)
#pragma unroll
      for (int ni = 0; ni < 4; ++ni)
        acc[mi][ni] = __builtin_amdgcn_mfma_f32_16x16x32_bf16(af[mi], bfr[ni], acc[mi][ni], 0, 0, 0);
    __syncthreads();
  }

#pragma unroll
  for (int ni = 0; ni < 4; ++ni) {
    int n = n0 + wn * 64 + ni * 16 + l15;
    float bo = bias[n];
#pragma unroll
    for (int mi = 0; mi < 4; ++mi) {
      int mb = m0 + wm * 64 + mi * 16 + quad * 4;
#pragma unroll
      for (int r = 0; r < 4; ++r) {
        int m = mb + r;
        if (m < M) C[(size_t)m * ldc + n] = acc[mi][ni][r] + bo;
      }
    }
  }
}

// ---------------- fused joint: out[m][v] = 0.1*(sum_h relu(enc[bt][h]+pred[bu][h])*Wout[v][h] + b_out[v])
// m = (b*T + t)*U + u, M=160000 (1250 blocks), N=1024 (8 blocks).
__global__ __launch_bounds__(256)
void fused_joint_kernel(const float* __restrict__ enc, const float* __restrict__ pred,
                        const __bf16* __restrict__ Wout, const float* __restrict__ b_out,
                        float* __restrict__ out) {
  __shared__ __bf16 As[128 * 40];   // padded stride 40 (ds_write'd, so padding is legal)
  __shared__ __bf16 Bs[128 * 32];   // global_load_lds'd -> must stay contiguous

  const int tid  = threadIdx.x;
  const int wave = tid >> 6, lane = tid & 63;
  const int l15  = lane & 15, quad = lane >> 4;
  const int wm   = wave & 1,  wn   = wave >> 1;
  const int n0 = blockIdx.x * 128;
  const int m0 = blockIdx.y * 128;

  // A-construction: 2 threads per row, 16 k-elements each
  const int r   = tid >> 1;
  const int kof = (tid & 1) << 4;
  const int m   = m0 + r;
  const int u   = m % U_;
  const int bt  = m / U_;            // = b*T + t
  const int b   = bt / T_;
  const float* encp  = enc  + (size_t)bt * H_ + kof;
  const float* predp = pred + ((size_t)b * U_ + u) * H_ + kof;
  __bf16* asp = As + r * 40 + kof;

  f32x4 acc[4][4];
#pragma unroll
  for (int i = 0; i < 4; ++i)
#pragma unroll
    for (int j = 0; j < 4; ++j) acc[i][j] = (f32x4){0.f, 0.f, 0.f, 0.f};

  for (int kk = 0; kk < H_; kk += 32) {
    // B panel: async stage 128x32 bf16 (8KB)
#pragma unroll
    for (int j = 0; j < 2; ++j) {
      int f   = (wave * 2 + j) * 1024 + lane * 16;
      int row = f >> 6;
      int kb  = (f & 63) >> 1;
      async_ld16(Wout + (size_t)(n0 + row) * H_ + kk + kb, (char*)Bs + (wave * 2 + j) * 1024);
    }
    // A tile: construct relu(enc+pred) -> bf16 -> LDS (overlaps with async B loads)
    f32x4 ef[4], pf[4];
#pragma unroll
    for (int i = 0; i < 4; ++i) {
      ef[i] = *(const f32x4*)(encp  + kk + i * 4);
      pf[i] = *(const f32x4*)(predp + kk + i * 4);
    }
    bf16x8 q0, q1;
#pragma unroll
    for (int i = 0; i < 8; ++i) {
      float v0 = fmaxf(ef[i >> 2][i & 3] + pf[i >> 2][i & 3], 0.f);
      float v1 = fmaxf(ef[(i + 8) >> 2][(i + 8) & 3] + pf[(i + 8) >> 2][(i + 8) & 3], 0.f);
      q0[i] = (__bf16)v0;
      q1[i] = (__bf16)v1;
    }
    *(bf16x8*)asp       = q0;
    *((bf16x8*)asp + 1) = q1;
    __syncthreads();

    bf16x8 af[4], bfr[4];
#pragma unroll
    for (int mi = 0; mi < 4; ++mi)
      af[mi] = *(const bf16x8*)(As + (wm * 64 + mi * 16 + l15) * 40 + quad * 8);
#pragma unroll
    for (int ni = 0; ni < 4; ++ni)
      bfr[ni] = *(const bf16x8*)(Bs + (wn * 64 + ni * 16 + l15) * 32 + quad * 8);
#pragma unroll
    for (int mi = 0; mi < 4; ++mi)
#pragma unroll
      for (int ni = 0; ni < 4; ++ni)
        acc[mi][ni] = __builtin_amdgcn_mfma_f32_16x16x32_bf16(af[mi], bfr[ni], acc[mi][ni], 0, 0, 0);
    __syncthreads();
  }

#pragma unroll
  for (int ni = 0; ni < 4; ++ni) {
    int n = n0 + wn * 64 + ni * 16 + l15;
    float bo = b_out[n];
#pragma unroll
    for (int mi = 0; mi < 4; ++mi) {
      size_t mb = (size_t)m0 + wm * 64 + mi * 16 + quad * 4;
      float* op = out + mb * V_ + n;
#pragma unroll
      for (int rr = 0; rr < 4; ++rr)
        op[(size_t)rr * V_] = (acc[mi][ni][rr] + bo) * 0.1f;
    }
  }
}

extern "C" void kernel_launch(void* const* d_in, const int* in_sizes, int n_in,
                              void* d_out, int out_size, void* d_ws, size_t ws_size,
                              hipStream_t stream) {
  const float* encoder   = (const float*)d_in[0];  // (8,200,512)
  const float* predictor = (const float*)d_in[1];  // (8,100,640)
  const float* W_enc     = (const float*)d_in[2];  // (512,512)
  const float* b_enc     = (const float*)d_in[3];  // (512,)
  const float* W_pred    = (const float*)d_in[4];  // (512,640)
  const float* b_pred    = (const float*)d_in[5];  // (512,)
  const float* W_out     = (const float*)d_in[6];  // (1024,512)
  const float* b_out     = (const float*)d_in[7];  // (1024,)
  float* out = (float*)d_out;

  char* ws = (char*)d_ws;
  size_t off = 0;
  auto alloc = [&](size_t bytes) { char* p = ws + off; off += (bytes + 255) & ~(size_t)255; return p; };

  float*  enc_f    = (float*)alloc((size_t)1600 * 512 * 4);
  float*  pred_f   = (float*)alloc((size_t)800 * 512 * 4);
  __bf16* enc_bf   = (__bf16*)alloc((size_t)1600 * 512 * 2);
  __bf16* Wenc_bf  = (__bf16*)alloc((size_t)512 * 512 * 2);
  __bf16* pred_bf  = (__bf16*)alloc((size_t)800 * 640 * 2);
  __bf16* Wpred_bf = (__bf16*)alloc((size_t)512 * 640 * 2);
  __bf16* Wout_bf  = (__bf16*)alloc((size_t)1024 * 512 * 2);

  auto cvt = [&](const float* src, __bf16* dst, int n) {
    cvt_bf16_kernel<<<(n + 1023) / 1024, 256, 0, stream>>>(src, dst, n);
  };
  cvt(encoder,   enc_bf,   1600 * 512);   // 819200
  cvt(W_enc,     Wenc_bf,  512 * 512);
  cvt(predictor, pred_bf,  800 * 640);    // 512000
  cvt(W_pred,    Wpred_bf, 512 * 640);
  cvt(W_out,     Wout_bf,  1024 * 512);

  // enc = encoder @ W_enc^T + b_enc  -> (1600,512) fp32
  gemm_bias_kernel<<<dim3(4, 13), 256, 0, stream>>>(enc_bf, Wenc_bf, b_enc, enc_f, 1600, 512, 512);
  // pred = predictor @ W_pred^T + b_pred -> (800,512) fp32
  gemm_bias_kernel<<<dim3(4, 7), 256, 0, stream>>>(pred_bf, Wpred_bf, b_pred, pred_f, 800, 640, 512);

  // fused joint + output projection
  fused_joint_kernel<<<dim3(8, 1250), 256, 0, stream>>>(enc_f, pred_f, Wout_bf, b_out, out);
}